// Round 5
// baseline (66.383 us; speedup 1.0000x reference)
//
#include <hip/hip_runtime.h>

#define MOM 0.9f
#define ONE_MINUS_MOM 0.1f
#define MAXK 16

// K_A: fused kernel.
//  blocks [0, B):        per-row argmax of scores (first-max tie-break, matching
//                        np.argmax), emit key[i] = (label<<1) | (pred != label).
//                        Also zero cnt[] (blocks 0..C/4).
//  blocks [B, B+C/4):    copy bank -> out_bank (one wave per class, 4/block) and
//                        times -> out_times. Independent of argmax; overlaps it.
__global__ __launch_bounds__(256) void fused_argmax_copy_kernel(
    const float* __restrict__ scores, const int* __restrict__ labels,
    const float* __restrict__ bank, const float* __restrict__ times,
    int* __restrict__ key, int* __restrict__ cnt,
    float* __restrict__ out_bank, float* __restrict__ out_times,
    int B, int C, int D)
{
    if ((int)blockIdx.x >= B) {
        // ---- copy blocks ----
        const int cb = blockIdx.x - B;
        const int lane = threadIdx.x & 63;
        const int wid  = threadIdx.x >> 6;
        const int l = (cb << 2) | wid;
        if (l >= C) return;
        const float4* brow = (const float4*)(bank + (size_t)l * D);
        float4* orow = (float4*)(out_bank + (size_t)l * D);
        const int nv = D >> 2;
        for (int v = lane; v < nv; v += 64) orow[v] = brow[v];
        if (lane == 0) out_times[l] = times[l];
        return;
    }

    // ---- argmax blocks ----
    // fold cnt zeroing into the first ceil(C/4) blocks
    if (threadIdx.x < 4) {
        int l = ((int)blockIdx.x << 2) | (int)threadIdx.x;
        if (l < C) cnt[l] = 0;
    }

    const int row = blockIdx.x;
    const float* rp = scores + (size_t)row * C;
    const int nv = C >> 2;
    const float4* r4 = (const float4*)rp;

    // 4 independent (value, float4-index) chains -> no 4-deep dependent
    // compare chain per loaded float4
    float b0 = -__builtin_inff(), b1 = b0, b2 = b0, b3 = b0;
    int v0 = 0x7fffffff, v1 = v0, v2 = v0, v3 = v0;
    for (int v = threadIdx.x; v < nv; v += 256) {
        float4 s = r4[v];
        if (s.x > b0) { b0 = s.x; v0 = v; }
        if (s.y > b1) { b1 = s.y; v1 = v; }
        if (s.z > b2) { b2 = s.z; v2 = v; }
        if (s.w > b3) { b3 = s.w; v3 = v; }
    }
    // merge chains: value desc, overall index asc (np.argmax first-max)
    float best = b0; int bidx = (v0 << 2) | 0;
    { int oi = (v1 << 2) | 1; if (b1 > best || (b1 == best && oi < bidx)) { best = b1; bidx = oi; } }
    { int oi = (v2 << 2) | 2; if (b2 > best || (b2 == best && oi < bidx)) { best = b2; bidx = oi; } }
    { int oi = (v3 << 2) | 3; if (b3 > best || (b3 == best && oi < bidx)) { best = b3; bidx = oi; } }
    // scalar tail (none when C % 4 == 0)
    for (int c = (nv << 2) + threadIdx.x; c < C; c += 256) {
        float s = rp[c];
        if (s > best) { best = s; bidx = c; }
    }

    // in-wave butterfly reduce (value desc, index asc tie-break)
    #pragma unroll
    for (int off = 32; off > 0; off >>= 1) {
        float ov = __shfl_xor(best, off);
        int   oi = __shfl_xor(bidx, off);
        if (ov > best || (ov == best && oi < bidx)) { best = ov; bidx = oi; }
    }

    __shared__ float sv[4];
    __shared__ int   si[4];
    const int lane = threadIdx.x & 63;
    const int wid  = threadIdx.x >> 6;
    if (lane == 0) { sv[wid] = best; si[wid] = bidx; }
    __syncthreads();
    if (threadIdx.x == 0) {
        float bv = sv[0]; int bi = si[0];
        #pragma unroll
        for (int w = 1; w < 4; ++w) {
            float ov = sv[w]; int oi = si[w];
            if (ov > bv || (ov == bv && oi < bi)) { bv = ov; bi = oi; }
        }
        int lab = labels[row];
        key[row] = (lab << 1) | ((bi != lab) ? 1 : 0);
    }
}

// K_B: one wave per sample i. One ballot sweep over key[] yields both
//   e = # earlier chosen samples with same label (the sample's rank)
//   c = # later chosen samples with same label
// Chosen sample i goes to slot[class*MAXK + e]; the unique e==0 sample
// writes cnt[class] = e + c + 1. No atomics, no scan, deterministic.
__global__ __launch_bounds__(256) void rank_kernel(
    const int* __restrict__ key, int* __restrict__ cnt,
    int* __restrict__ slot, int B)
{
    const int lane = threadIdx.x & 63;
    const int i = blockIdx.x * 4 + (threadIdx.x >> 6);
    if (i >= B) return;
    const int mykey = key[i];
    if (!(mykey & 1)) return;   // not chosen

    int e = 0, c = 0;
    for (int base = 0; base < B; base += 64) {
        int j = base + lane;
        int kj = (j < B) ? key[j] : -1;
        bool match = (kj == mykey);
        e += __popcll(__ballot(match && (j < i)));
        c += __popcll(__ballot(match && (j > i)));
    }
    if (lane == 0) {
        int l = mykey >> 1;
        if (e < MAXK) slot[l * MAXK + e] = i;
        if (e == 0) cnt[l] = c + 1;
    }
}

// K_C: one WAVE per class (4/block), ONLY k>0 classes do work (others exit on
// an L2-hot cnt read; the fused kernel's copy already produced their output).
// out = m^k * bank + sum_r w_r * feat[slot_r], ranks descending so the weight
// is a running multiply. No LDS, no barriers.
__global__ __launch_bounds__(256) void update_kernel(
    const float* __restrict__ bank, const float* __restrict__ times,
    const float* __restrict__ feat, const int* __restrict__ cnt,
    const int* __restrict__ slot,
    float* __restrict__ out_bank, float* __restrict__ out_times, int C, int D)
{
    const int lane = threadIdx.x & 63;
    const int wid  = threadIdx.x >> 6;
    const int l = (blockIdx.x << 2) | wid;
    if (l >= C) return;

    const int k = cnt[l];
    if (k == 0) return;   // copy from fused kernel already correct
    const int kk = (k < MAXK) ? k : MAXK;
    float scale = 1.0f;
    for (int p = 0; p < k; ++p) scale *= MOM;

    const float4* brow = (const float4*)(bank + (size_t)l * D);
    float4* orow = (float4*)(out_bank + (size_t)l * D);
    const int sbase = l * MAXK;
    const int nv = D >> 2;

    if (nv == 256) {
        float4 a0 = brow[lane];
        float4 a1 = brow[lane + 64];
        float4 a2 = brow[lane + 128];
        float4 a3 = brow[lane + 192];
        a0.x *= scale; a0.y *= scale; a0.z *= scale; a0.w *= scale;
        a1.x *= scale; a1.y *= scale; a1.z *= scale; a1.w *= scale;
        a2.x *= scale; a2.y *= scale; a2.z *= scale; a2.w *= scale;
        a3.x *= scale; a3.y *= scale; a3.z *= scale; a3.w *= scale;
        float wgt = ONE_MINUS_MOM;
        for (int r = kk - 1; r >= 0; --r) {
            int j = slot[sbase + r];
            const float4* f4 = (const float4*)(feat + (size_t)j * D);
            float4 f0 = f4[lane];
            float4 f1 = f4[lane + 64];
            float4 f2 = f4[lane + 128];
            float4 f3 = f4[lane + 192];
            a0.x += wgt * f0.x; a0.y += wgt * f0.y; a0.z += wgt * f0.z; a0.w += wgt * f0.w;
            a1.x += wgt * f1.x; a1.y += wgt * f1.y; a1.z += wgt * f1.z; a1.w += wgt * f1.w;
            a2.x += wgt * f2.x; a2.y += wgt * f2.y; a2.z += wgt * f2.z; a2.w += wgt * f2.w;
            a3.x += wgt * f3.x; a3.y += wgt * f3.y; a3.z += wgt * f3.z; a3.w += wgt * f3.w;
            wgt *= MOM;
        }
        orow[lane] = a0;
        orow[lane + 64] = a1;
        orow[lane + 128] = a2;
        orow[lane + 192] = a3;
    } else {
        for (int v = lane; v < nv; v += 64) {
            float4 a = brow[v];
            a.x *= scale; a.y *= scale; a.z *= scale; a.w *= scale;
            float wgt = ONE_MINUS_MOM;
            for (int r = kk - 1; r >= 0; --r) {
                int j = slot[sbase + r];
                const float4* f4 = (const float4*)(feat + (size_t)j * D);
                float4 f = f4[v];
                a.x += wgt * f.x; a.y += wgt * f.y; a.z += wgt * f.z; a.w += wgt * f.w;
                wgt *= MOM;
            }
            orow[v] = a;
        }
    }
    if (lane == 0) out_times[l] = times[l] + (float)k;
}

extern "C" void kernel_launch(void* const* d_in, const int* in_sizes, int n_in,
                              void* d_out, int out_size, void* d_ws, size_t ws_size,
                              hipStream_t stream) {
    const float* scores = (const float*)d_in[0];
    const float* feat   = (const float*)d_in[1];
    const float* bank   = (const float*)d_in[2];
    const float* times  = (const float*)d_in[3];
    const int*   labels = (const int*)d_in[4];

    const int B = in_sizes[4];            // 4096
    const int C = in_sizes[3];            // 10000
    const int D = in_sizes[1] / B;        // 1024

    float* out_bank  = (float*)d_out;
    float* out_times = out_bank + (size_t)C * D;

    int* key  = (int*)d_ws;               // B
    int* cnt  = key + B;                  // C
    int* slot = cnt + C;                  // C * MAXK

    const int copy_blocks = (C + 3) / 4;
    fused_argmax_copy_kernel<<<B + copy_blocks, 256, 0, stream>>>(
        scores, labels, bank, times, key, cnt, out_bank, out_times, B, C, D);
    rank_kernel<<<(B + 3) / 4, 256, 0, stream>>>(key, cnt, slot, B);
    update_kernel<<<(C + 3) / 4, 256, 0, stream>>>(bank, times, feat, cnt, slot,
                                                   out_bank, out_times, C, D);
}